// Round 3
// baseline (788.378 us; speedup 1.0000x reference)
//
#include <hip/hip_runtime.h>

// ONN conv2d: B=16, Cin=128, H=W=32, Cout=256, k=3 (pad=1, stride=1)
// N=16384 positions, D=1152=18*64 chunks of VEC=64, M=256.
// out[n,m] = sum_r sign01( dot_c( x[n,64r+c], wq[64r+c,m] ) )
// wq = clamp(rintf(w*scale), -7, 7), scale = fl32(15/(fl32(max-min)+1e-9f))
//
// Main path: bf16 MFMA with x split hi/lo (w int4 exact in bf16).
// |mfma_dot - ref_fp32_chain| < ~2e-3; dots with |s| < TAU=0.03 are recomputed
// bit-exactly (sequential fp32, ascending c, separate mul/add) by k_fix.

#define TAU 0.03f
#define CAP_MAX 262144

typedef short short8 __attribute__((ext_vector_type(8)));
typedef float f32x4 __attribute__((ext_vector_type(4)));
typedef unsigned int uv4u __attribute__((ext_vector_type(4), aligned(4)));   // unaligned-ok loads
typedef unsigned int uv4 __attribute__((ext_vector_type(4)));                // 16B-aligned
typedef unsigned int uv2 __attribute__((ext_vector_type(2)));

__device__ __forceinline__ unsigned short bf16rn(float v) {
    unsigned u = __float_as_uint(v);
    unsigned r = u + 0x7fffu + ((u >> 16) & 1u);
    return (unsigned short)(r >> 16);
}

// ---------------- prep: weight min/max + scale ----------------
__global__ __launch_bounds__(256) void k_minmax(const float* __restrict__ w,
                                                float* __restrict__ pmin,
                                                float* __restrict__ pmax) {
    int tid = blockIdx.x * blockDim.x + threadIdx.x;
    float vmin = 1e30f, vmax = -1e30f;
    for (int i = tid; i < 294912; i += gridDim.x * blockDim.x) {
        float v = w[i];
        vmin = fminf(vmin, v);
        vmax = fmaxf(vmax, v);
    }
    #pragma unroll
    for (int off = 32; off > 0; off >>= 1) {
        vmin = fminf(vmin, __shfl_down(vmin, off, 64));
        vmax = fmaxf(vmax, __shfl_down(vmax, off, 64));
    }
    __shared__ float smin[4], smax[4];
    int wave = threadIdx.x >> 6;
    if ((threadIdx.x & 63) == 0) { smin[wave] = vmin; smax[wave] = vmax; }
    __syncthreads();
    if (threadIdx.x == 0) {
        #pragma unroll
        for (int i = 1; i < 4; i++) {
            vmin = fminf(vmin, smin[i]);
            vmax = fmaxf(vmax, smax[i]);
        }
        pmin[blockIdx.x] = vmin;
        pmax[blockIdx.x] = vmax;
    }
}

__global__ void k_scale(const float* __restrict__ pmin, const float* __restrict__ pmax,
                        float* __restrict__ scale, unsigned* __restrict__ cnt) {
    float vmin = pmin[threadIdx.x];
    float vmax = pmax[threadIdx.x];
    #pragma unroll
    for (int off = 32; off > 0; off >>= 1) {
        vmin = fminf(vmin, __shfl_down(vmin, off, 64));
        vmax = fmaxf(vmax, __shfl_down(vmax, off, 64));
    }
    if (threadIdx.x == 0) {
        float t = __fadd_rn(__fsub_rn(vmax, vmin), 1e-9f);
        *scale = __fdiv_rn(15.0f, t);
        *cnt = 0u;
    }
}

// ---------------- prep: quantize weights into MFMA A-fragment order ----------------
// slot = ((g*18 + r)*8 + mt*2 + khalf)*64 + lane ; 16B per slot (8 bf16, k ascending)
// value(lane, j) = wq[d = 64r + khalf*32 + (lane>>4)*8 + j][m = g*64 + mt*16 + (lane&15)]
__global__ __launch_bounds__(256) void k_quantb(const float* __restrict__ w,
                                                const float* __restrict__ scale,
                                                uv4* __restrict__ wqb) {
    int slot = blockIdx.x * 256 + threadIdx.x;   // 36864 total
    int lane = slot & 63;
    int sub = slot >> 6;
    int khalf = sub & 1;
    int mt = (sub >> 1) & 3;
    int gr = sub >> 3;                 // g*18 + r
    int g = gr / 18, r = gr - g * 18;
    int m = g * 64 + mt * 16 + (lane & 15);
    int dbase = r * 64 + khalf * 32 + (lane >> 4) * 8;
    float s = *scale;
    const float* wp = w + (size_t)m * 1152 + dbase;
    unsigned o[4];
    #pragma unroll
    for (int p = 0; p < 4; ++p) {
        float q0 = rintf(__fmul_rn(wp[2 * p], s));
        float q1 = rintf(__fmul_rn(wp[2 * p + 1], s));
        q0 = fminf(fmaxf(q0, -7.0f), 7.0f);
        q1 = fminf(fmaxf(q1, -7.0f), 7.0f);
        o[p] = (unsigned)bf16rn(q0) | ((unsigned)bf16rn(q1) << 16);
    }
    uv4 v; v.x = o[0]; v.y = o[1]; v.z = o[2]; v.w = o[3];
    wqb[slot] = v;
}

// ---------------- prep: zero-padded hi/lo bf16 planes ----------------
// xpk[bc][yy][xx], yy,xx in [0,34), u32 = lo16<<16 | hi16, zero halo
__global__ __launch_bounds__(256) void k_pad(const float* __restrict__ inp,
                                             unsigned* __restrict__ xpk) {
    int bc = blockIdx.x;                       // b*128 + cin (2048)
    const float* src = inp + (size_t)bc * 1024;
    unsigned* dst = xpk + (size_t)bc * 1156;
    #pragma unroll
    for (int i = 0; i < 5; ++i) {
        int idx = threadIdx.x + i * 256;
        if (idx < 1156) {
            int yy = idx / 34, xx = idx - yy * 34;
            float v = 0.0f;
            int ys = yy - 1, xs_ = xx - 1;
            if ((unsigned)ys < 32u && (unsigned)xs_ < 32u) v = src[ys * 32 + xs_];
            unsigned short h = bf16rn(v);
            float hf = __uint_as_float((unsigned)h << 16);
            unsigned short l = bf16rn(v - hf);
            dst[idx] = (unsigned)h | ((unsigned)l << 16);
        }
    }
}

// ---------------- main: MFMA GEMM-sign ----------------
__global__ __launch_bounds__(256) void k_main(const unsigned* __restrict__ xpk,
                                              const uv4* __restrict__ wqb,
                                              float* __restrict__ out,
                                              unsigned* __restrict__ cnt,
                                              unsigned* __restrict__ list,
                                              int cap) {
    __shared__ unsigned xs[64 * 66];   // [k][n] packed hi|lo, stride 66 (2-way banks)
    __shared__ uv4 asld[512];          // A frags for this chunk (8 KB)

    const int t = threadIdx.x;
    const int lane = t & 63;
    const int wv = t >> 6;             // wave id = n-tile
    const int quad = lane >> 4;
    const int nl = lane & 15;
    const int n0 = blockIdx.x * 64;
    const int g = blockIdx.y;
    const int b = n0 >> 10;

    // staging mapping: thread -> (k row, 16-n segment)
    const int sk = t >> 2;
    const int sseg = t & 3;
    const int sy = ((n0 & 1023) >> 5) + (sseg >> 1);  // image row (0..31)
    const int sx0 = (sseg & 1) * 16;
    int cin = sk / 9;
    int rem9 = sk - cin * 9;
    const unsigned* xbase = xpk + (size_t)b * (128 * 1156);

    int counts[4][4] = {};
    const int aslotbase = g * 18 * 512;

    for (int r = 0; r < 18; ++r) {
        // ---- stage A frags (global, already frag-ordered) ----
        asld[t] = wqb[aslotbase + r * 512 + t];
        asld[t + 256] = wqb[aslotbase + r * 512 + t + 256];
        // ---- stage X tile: 16 contiguous u32 from padded plane row ----
        {
            int kh = rem9 / 3;
            int kw = rem9 - kh * 3;
            const unsigned* srow = xbase + cin * 1156 + (sy + kh) * 34 + kw + sx0;
            uv4u v0 = *(const uv4u*)(srow + 0);
            uv4u v1 = *(const uv4u*)(srow + 4);
            uv4u v2 = *(const uv4u*)(srow + 8);
            uv4u v3 = *(const uv4u*)(srow + 12);
            uv2* d2 = (uv2*)&xs[sk * 66 + sseg * 16];
            uv2 w0; w0.x = v0.x; w0.y = v0.y; d2[0] = w0;
            uv2 w1; w1.x = v0.z; w1.y = v0.w; d2[1] = w1;
            uv2 w2; w2.x = v1.x; w2.y = v1.y; d2[2] = w2;
            uv2 w3; w3.x = v1.z; w3.y = v1.w; d2[3] = w3;
            uv2 w4; w4.x = v2.x; w4.y = v2.y; d2[4] = w4;
            uv2 w5; w5.x = v2.z; w5.y = v2.w; d2[5] = w5;
            uv2 w6; w6.x = v3.x; w6.y = v3.y; d2[6] = w6;
            uv2 w7; w7.x = v3.z; w7.y = v3.w; d2[7] = w7;
        }
        // incremental d += 64 decode state (64 = 7*9 + 1)
        rem9 += 1;
        if (rem9 == 9) { rem9 = 0; cin += 8; } else { cin += 7; }

        __syncthreads();

        // ---- A fragments ----
        short8 af[4][2];
        #pragma unroll
        for (int mt = 0; mt < 4; ++mt)
            #pragma unroll
            for (int kh2 = 0; kh2 < 2; ++kh2) {
                uv4 u = asld[(mt * 2 + kh2) * 64 + lane];
                af[mt][kh2] = __builtin_bit_cast(short8, u);
            }

        // ---- B fragments (split packed hi|lo) ----
        short8 bhi[2], blo[2];
        {
            const int base = quad * 8 * 66 + wv * 16 + nl;
            #pragma unroll
            for (int kh2 = 0; kh2 < 2; ++kh2) {
                unsigned u[8];
                #pragma unroll
                for (int j = 0; j < 8; ++j)
                    u[j] = xs[base + (kh2 * 32 + j) * 66];
                union { unsigned d[4]; short8 v; } H, L;
                #pragma unroll
                for (int p = 0; p < 4; ++p) {
                    unsigned ua = u[2 * p], ub = u[2 * p + 1];
                    H.d[p] = (ua & 0xffffu) | (ub << 16);
                    L.d[p] = (ua >> 16) | (ub & 0xffff0000u);
                }
                bhi[kh2] = H.v;
                blo[kh2] = L.v;
            }
        }

        // ---- MFMA per m-tile, binarize, borderline detect ----
        #pragma unroll
        for (int mt = 0; mt < 4; ++mt) {
            f32x4 acc = {0.0f, 0.0f, 0.0f, 0.0f};
            acc = __builtin_amdgcn_mfma_f32_16x16x32_bf16(af[mt][0], bhi[0], acc, 0, 0, 0);
            acc = __builtin_amdgcn_mfma_f32_16x16x32_bf16(af[mt][1], bhi[1], acc, 0, 0, 0);
            acc = __builtin_amdgcn_mfma_f32_16x16x32_bf16(af[mt][0], blo[0], acc, 0, 0, 0);
            acc = __builtin_amdgcn_mfma_f32_16x16x32_bf16(af[mt][1], blo[1], acc, 0, 0, 0);
            #pragma unroll
            for (int i = 0; i < 4; ++i) {
                float s = acc[i];
                int ge = (s >= 0.0f) ? 1 : 0;
                counts[mt][i] += ge;
                if (__builtin_fabsf(s) < TAU) {
                    unsigned idx = atomicAdd(cnt, 1u);
                    if (idx < (unsigned)cap) {
                        unsigned m = (unsigned)(g * 64 + mt * 16 + quad * 4 + i);
                        unsigned n = (unsigned)(n0 + wv * 16 + nl);
                        list[idx] = n | ((unsigned)r << 14) | (m << 19) | ((unsigned)ge << 27);
                    }
                }
            }
        }
        __syncthreads();
    }

    // ---- epilogue: C/D layout col=lane&15 (n), row=quad*4+reg (m) ----
    const int n = n0 + wv * 16 + nl;
    const int p = n & 1023;
    #pragma unroll
    for (int mt = 0; mt < 4; ++mt)
        #pragma unroll
        for (int i = 0; i < 4; ++i) {
            int m = g * 64 + mt * 16 + quad * 4 + i;
            out[(((size_t)(b * 256 + m)) << 10) + p] = (float)counts[mt][i];
        }
}

// ---------------- fixup: bit-exact recompute of borderline dots ----------------
__global__ __launch_bounds__(256) void k_fix(const float* __restrict__ inp,
                                             const float* __restrict__ weight,
                                             const float* __restrict__ scale,
                                             const unsigned* __restrict__ cnt,
                                             const unsigned* __restrict__ list,
                                             float* __restrict__ out, int cap) {
    unsigned total = *cnt;
    if (total > (unsigned)cap) total = (unsigned)cap;
    float sc = *scale;
    for (unsigned i = blockIdx.x * 256 + threadIdx.x; i < total; i += gridDim.x * 256) {
        unsigned u = list[i];
        int n = u & 16383;
        int r = (u >> 14) & 31;
        int m = (u >> 19) & 255;
        int bit = (u >> 27) & 1;
        int b = n >> 10, p = n & 1023, y = p >> 5, x = p & 31;
        const float* ib = inp + (size_t)b * (128 * 32 * 32);
        const float* wp = weight + (size_t)m * 1152;
        float s = 0.0f;
        int d = r * 64;
        for (int c = 0; c < 64; ++c, ++d) {
            int ci = d / 9, rem = d - ci * 9;
            int kh = rem / 3, kw = rem - kh * 3;
            int yy = y + kh - 1, xx = x + kw - 1;
            float xv = 0.0f;
            if ((unsigned)yy < 32u && (unsigned)xx < 32u)
                xv = ib[(ci * 32 + yy) * 32 + xx];
            float q = rintf(__fmul_rn(wp[d], sc));
            q = fminf(fmaxf(q, -7.0f), 7.0f);
            s = __fadd_rn(s, __fmul_rn(xv, q));
        }
        int nb = (s >= 0.0f) ? 1 : 0;
        if (nb != bit)
            atomicAdd(&out[(((size_t)(b * 256 + m)) << 10) + p], nb ? 1.0f : -1.0f);
    }
}

extern "C" void kernel_launch(void* const* d_in, const int* in_sizes, int n_in,
                              void* d_out, int out_size, void* d_ws, size_t ws_size,
                              hipStream_t stream) {
    const float* inp    = (const float*)d_in[0];   // [16,128,32,32]
    const float* weight = (const float*)d_in[1];   // [256,128,3,3]
    float* out = (float*)d_out;                    // [16,256,32,32]

    char* ws = (char*)d_ws;
    float*    pmin  = (float*)(ws + 0);
    float*    pmax  = (float*)(ws + 256);
    float*    scale = (float*)(ws + 512);
    unsigned* cnt   = (unsigned*)(ws + 516);
    uv4*      wqb   = (uv4*)(ws + 1024);          // 589,824 B
    unsigned* xpk   = (unsigned*)(ws + 590848);   // 9,469,952 B
    unsigned* list  = (unsigned*)(ws + 10060800); // up to 1 MB

    size_t avail = (ws_size > 10060800) ? (ws_size - 10060800) / 4 : 0;
    int cap = (int)(avail < CAP_MAX ? avail : CAP_MAX);

    k_minmax<<<64, 256, 0, stream>>>(weight, pmin, pmax);
    k_scale<<<1, 64, 0, stream>>>(pmin, pmax, scale, cnt);
    k_quantb<<<144, 256, 0, stream>>>(weight, scale, wqb);
    k_pad<<<2048, 256, 0, stream>>>(inp, xpk);

    dim3 grid(256, 4);   // (N/64, M/64)
    k_main<<<grid, 256, 0, stream>>>(xpk, wqb, out, cnt, list, cap);
    k_fix<<<64, 256, 0, stream>>>(inp, weight, scale, cnt, list, out, cap);
}

// Round 4
// 212.440 us; speedup vs baseline: 3.7111x; 3.7111x over previous
//
#include <hip/hip_runtime.h>

// ONN conv2d: B=16, Cin=128, H=W=32, Cout=256, k=3 (pad=1, stride=1)
// N=16384 positions, D=1152=18*64 chunks of VEC=64, M=256.
// out[n,m] = sum_r sign01( dot_c( x[n,64r+c], wq[64r+c,m] ) )
// wq = clamp(rintf(w*scale), -7, 7), scale = fl32(15/(fl32(max-min)+1e-9f))
//
// Main path: bf16 MFMA with x split hi/lo (w int4 exact in bf16).
// |mfma_dot - ref_fp32_chain| < ~2e-3; dots with |s| < TAU=0.03 are recomputed
// bit-exactly (sequential fp32, ascending c, separate mul/add) by k_fix.
// Borderline hits buffered per-block in LDS (one global atomic per block) --
// round 3 showed per-dot device-scope atomics stall the whole kernel.

#define TAU 0.03f
#define CAP_MAX 262144
#define HITCAP 2048

typedef short short8 __attribute__((ext_vector_type(8)));
typedef float f32x4 __attribute__((ext_vector_type(4)));
typedef unsigned int uv4u __attribute__((ext_vector_type(4), aligned(4)));   // unaligned-ok loads
typedef unsigned int uv4 __attribute__((ext_vector_type(4)));                // 16B-aligned
typedef unsigned int uv2 __attribute__((ext_vector_type(2)));

__device__ __forceinline__ unsigned short bf16rn(float v) {
    unsigned u = __float_as_uint(v);
    unsigned r = u + 0x7fffu + ((u >> 16) & 1u);
    return (unsigned short)(r >> 16);
}

// ---------------- prep: weight min/max partials ----------------
__global__ __launch_bounds__(256) void k_minmax(const float* __restrict__ w,
                                                float* __restrict__ pmin,
                                                float* __restrict__ pmax,
                                                unsigned* __restrict__ cnt) {
    if (blockIdx.x == 0 && threadIdx.x == 0) *cnt = 0u;
    int tid = blockIdx.x * blockDim.x + threadIdx.x;
    float vmin = 1e30f, vmax = -1e30f;
    for (int i = tid; i < 294912; i += gridDim.x * blockDim.x) {
        float v = w[i];
        vmin = fminf(vmin, v);
        vmax = fmaxf(vmax, v);
    }
    #pragma unroll
    for (int off = 32; off > 0; off >>= 1) {
        vmin = fminf(vmin, __shfl_down(vmin, off, 64));
        vmax = fmaxf(vmax, __shfl_down(vmax, off, 64));
    }
    __shared__ float smin[4], smax[4];
    int wave = threadIdx.x >> 6;
    if ((threadIdx.x & 63) == 0) { smin[wave] = vmin; smax[wave] = vmax; }
    __syncthreads();
    if (threadIdx.x == 0) {
        #pragma unroll
        for (int i = 1; i < 4; i++) {
            vmin = fminf(vmin, smin[i]);
            vmax = fmaxf(vmax, smax[i]);
        }
        pmin[blockIdx.x] = vmin;
        pmax[blockIdx.x] = vmax;
    }
}

// block-local scale from the 64 partials (identical fp32 op sequence everywhere)
__device__ __forceinline__ float block_scale(const float* pmin, const float* pmax,
                                             float* sca_lds) {
    int t = threadIdx.x;
    if (t < 64) {
        float vmin = pmin[t];
        float vmax = pmax[t];
        #pragma unroll
        for (int off = 32; off > 0; off >>= 1) {
            vmin = fminf(vmin, __shfl_down(vmin, off, 64));
            vmax = fmaxf(vmax, __shfl_down(vmax, off, 64));
        }
        if (t == 0) {
            float tt = __fadd_rn(__fsub_rn(vmax, vmin), 1e-9f);
            *sca_lds = __fdiv_rn(15.0f, tt);
        }
    }
    __syncthreads();
    return *sca_lds;
}

// ---------------- prep: quantize weights into MFMA A-fragment order ----------------
// slot = ((g*18 + r)*8 + mt*2 + khalf)*64 + lane ; 16B per slot (8 bf16, k ascending)
// value(lane, j) = wq[d = 64r + khalf*32 + (lane>>4)*8 + j][m = g*64 + mt*16 + (lane&15)]
__global__ __launch_bounds__(256) void k_quantb(const float* __restrict__ w,
                                                const float* __restrict__ pmin,
                                                const float* __restrict__ pmax,
                                                uv4* __restrict__ wqb) {
    __shared__ float sca;
    float s = block_scale(pmin, pmax, &sca);
    int slot = blockIdx.x * 256 + threadIdx.x;   // 36864 total
    int lane = slot & 63;
    int sub = slot >> 6;
    int khalf = sub & 1;
    int mt = (sub >> 1) & 3;
    int gr = sub >> 3;                 // g*18 + r
    int g = gr / 18, r = gr - g * 18;
    int m = g * 64 + mt * 16 + (lane & 15);
    int dbase = r * 64 + khalf * 32 + (lane >> 4) * 8;
    const float* wp = w + (size_t)m * 1152 + dbase;
    unsigned o[4];
    #pragma unroll
    for (int p = 0; p < 4; ++p) {
        float q0 = rintf(__fmul_rn(wp[2 * p], s));
        float q1 = rintf(__fmul_rn(wp[2 * p + 1], s));
        q0 = fminf(fmaxf(q0, -7.0f), 7.0f);
        q1 = fminf(fmaxf(q1, -7.0f), 7.0f);
        o[p] = (unsigned)bf16rn(q0) | ((unsigned)bf16rn(q1) << 16);
    }
    uv4 v; v.x = o[0]; v.y = o[1]; v.z = o[2]; v.w = o[3];
    wqb[slot] = v;
}

// ---------------- prep: zero-padded hi/lo bf16 planes ----------------
// xpk[bc][yy][xx], yy,xx in [0,34), u32 = lo16<<16 | hi16, zero halo
__global__ __launch_bounds__(256) void k_pad(const float* __restrict__ inp,
                                             unsigned* __restrict__ xpk) {
    int bc = blockIdx.x;                       // b*128 + cin (2048)
    const float* src = inp + (size_t)bc * 1024;
    unsigned* dst = xpk + (size_t)bc * 1156;
    #pragma unroll
    for (int i = 0; i < 5; ++i) {
        int idx = threadIdx.x + i * 256;
        if (idx < 1156) {
            int yy = idx / 34, xx = idx - yy * 34;
            float v = 0.0f;
            int ys = yy - 1, xs_ = xx - 1;
            if ((unsigned)ys < 32u && (unsigned)xs_ < 32u) v = src[ys * 32 + xs_];
            unsigned short h = bf16rn(v);
            float hf = __uint_as_float((unsigned)h << 16);
            unsigned short l = bf16rn(v - hf);
            dst[idx] = (unsigned)h | ((unsigned)l << 16);
        }
    }
}

// ---------------- main: MFMA GEMM-sign ----------------
__global__ __launch_bounds__(256) void k_main(const unsigned* __restrict__ xpk,
                                              const uv4* __restrict__ wqb,
                                              float* __restrict__ out,
                                              unsigned* __restrict__ cnt,
                                              unsigned* __restrict__ list,
                                              int cap) {
    __shared__ unsigned xs[64 * 66];   // [k][n] packed hi|lo, stride 66 (2-way banks)
    __shared__ uv4 asld[512];          // A frags for this chunk (8 KB)
    __shared__ unsigned hitbuf[HITCAP];
    __shared__ unsigned hitcnt, hitbase;

    const int t = threadIdx.x;
    const int lane = t & 63;
    const int wv = t >> 6;             // wave id = n-tile
    const int quad = lane >> 4;
    const int nl = lane & 15;
    const int n0 = blockIdx.x * 64;
    const int g = blockIdx.y;
    const int b = n0 >> 10;

    if (t == 0) hitcnt = 0u;

    // staging mapping: thread -> (k row, 16-n segment)
    const int sk = t >> 2;
    const int sseg = t & 3;
    const int sy = ((n0 & 1023) >> 5) + (sseg >> 1);  // image row (0..31)
    const int sx0 = (sseg & 1) * 16;
    int cin = sk / 9;
    int rem9 = sk - cin * 9;
    const unsigned* xbase = xpk + (size_t)b * (128 * 1156);

    int counts[4][4] = {};
    const int aslotbase = g * 18 * 512;

    for (int r = 0; r < 18; ++r) {
        // ---- stage A frags (global, already frag-ordered) ----
        asld[t] = wqb[aslotbase + r * 512 + t];
        asld[t + 256] = wqb[aslotbase + r * 512 + t + 256];
        // ---- stage X tile: 16 contiguous u32 from padded plane row ----
        {
            int kh = rem9 / 3;
            int kw = rem9 - kh * 3;
            const unsigned* srow = xbase + cin * 1156 + (sy + kh) * 34 + kw + sx0;
            uv4u v0 = *(const uv4u*)(srow + 0);
            uv4u v1 = *(const uv4u*)(srow + 4);
            uv4u v2 = *(const uv4u*)(srow + 8);
            uv4u v3 = *(const uv4u*)(srow + 12);
            uv2* d2 = (uv2*)&xs[sk * 66 + sseg * 16];
            uv2 w0; w0.x = v0.x; w0.y = v0.y; d2[0] = w0;
            uv2 w1; w1.x = v0.z; w1.y = v0.w; d2[1] = w1;
            uv2 w2; w2.x = v1.x; w2.y = v1.y; d2[2] = w2;
            uv2 w3; w3.x = v1.z; w3.y = v1.w; d2[3] = w3;
            uv2 w4; w4.x = v2.x; w4.y = v2.y; d2[4] = w4;
            uv2 w5; w5.x = v2.z; w5.y = v2.w; d2[5] = w5;
            uv2 w6; w6.x = v3.x; w6.y = v3.y; d2[6] = w6;
            uv2 w7; w7.x = v3.z; w7.y = v3.w; d2[7] = w7;
        }
        // incremental d += 64 decode state (64 = 7*9 + 1)
        rem9 += 1;
        if (rem9 == 9) { rem9 = 0; cin += 8; } else { cin += 7; }

        __syncthreads();

        // ---- A fragments ----
        short8 af[4][2];
        #pragma unroll
        for (int mt = 0; mt < 4; ++mt)
            #pragma unroll
            for (int kh2 = 0; kh2 < 2; ++kh2) {
                uv4 u = asld[(mt * 2 + kh2) * 64 + lane];
                af[mt][kh2] = __builtin_bit_cast(short8, u);
            }

        // ---- B fragments (split packed hi|lo) ----
        short8 bhi[2], blo[2];
        {
            const int base = quad * 8 * 66 + wv * 16 + nl;
            #pragma unroll
            for (int kh2 = 0; kh2 < 2; ++kh2) {
                unsigned u[8];
                #pragma unroll
                for (int j = 0; j < 8; ++j)
                    u[j] = xs[base + (kh2 * 32 + j) * 66];
                union { unsigned d[4]; short8 v; } H, L;
                #pragma unroll
                for (int p = 0; p < 4; ++p) {
                    unsigned ua = u[2 * p], ub = u[2 * p + 1];
                    H.d[p] = (ua & 0xffffu) | (ub << 16);
                    L.d[p] = (ua >> 16) | (ub & 0xffff0000u);
                }
                bhi[kh2] = H.v;
                blo[kh2] = L.v;
            }
        }

        // ---- MFMA per m-tile, binarize, borderline -> LDS queue ----
        #pragma unroll
        for (int mt = 0; mt < 4; ++mt) {
            f32x4 acc = {0.0f, 0.0f, 0.0f, 0.0f};
            acc = __builtin_amdgcn_mfma_f32_16x16x32_bf16(af[mt][0], bhi[0], acc, 0, 0, 0);
            acc = __builtin_amdgcn_mfma_f32_16x16x32_bf16(af[mt][1], bhi[1], acc, 0, 0, 0);
            acc = __builtin_amdgcn_mfma_f32_16x16x32_bf16(af[mt][0], blo[0], acc, 0, 0, 0);
            acc = __builtin_amdgcn_mfma_f32_16x16x32_bf16(af[mt][1], blo[1], acc, 0, 0, 0);
            #pragma unroll
            for (int i = 0; i < 4; ++i) {
                float s = acc[i];
                int ge = (s >= 0.0f) ? 1 : 0;
                counts[mt][i] += ge;
                if (__builtin_fabsf(s) < TAU) {
                    unsigned idx = atomicAdd(&hitcnt, 1u);   // LDS atomic: fast
                    if (idx < (unsigned)HITCAP) {
                        unsigned m = (unsigned)(g * 64 + mt * 16 + quad * 4 + i);
                        unsigned n = (unsigned)(n0 + wv * 16 + nl);
                        hitbuf[idx] = n | ((unsigned)r << 14) | (m << 19) | ((unsigned)ge << 27);
                    }
                }
            }
        }
        __syncthreads();
    }

    // ---- epilogue: C/D layout col=lane&15 (n), row=quad*4+reg (m) ----
    const int n = n0 + wv * 16 + nl;
    const int p = n & 1023;
    #pragma unroll
    for (int mt = 0; mt < 4; ++mt)
        #pragma unroll
        for (int i = 0; i < 4; ++i) {
            int m = g * 64 + mt * 16 + quad * 4 + i;
            out[(((size_t)(b * 256 + m)) << 10) + p] = (float)counts[mt][i];
        }

    // ---- flush LDS hit queue: ONE global atomic per block + coalesced dump ----
    unsigned tot = hitcnt;
    if (tot > (unsigned)HITCAP) tot = (unsigned)HITCAP;
    if (t == 0) hitbase = atomicAdd(cnt, tot);
    __syncthreads();
    unsigned base = hitbase;
    for (unsigned i = t; i < tot; i += 256)
        if (base + i < (unsigned)cap) list[base + i] = hitbuf[i];
}

// ---------------- fixup: bit-exact recompute of borderline dots ----------------
__global__ __launch_bounds__(256) void k_fix(const float* __restrict__ inp,
                                             const float* __restrict__ weight,
                                             const float* __restrict__ pmin,
                                             const float* __restrict__ pmax,
                                             const unsigned* __restrict__ cnt,
                                             const unsigned* __restrict__ list,
                                             float* __restrict__ out, int cap) {
    __shared__ float sca;
    float sc = block_scale(pmin, pmax, &sca);
    unsigned total = *cnt;
    if (total > (unsigned)cap) total = (unsigned)cap;
    for (unsigned i = blockIdx.x * 256 + threadIdx.x; i < total; i += gridDim.x * 256) {
        unsigned u = list[i];
        int n = u & 16383;
        int r = (u >> 14) & 31;
        int m = (u >> 19) & 255;
        int bit = (u >> 27) & 1;
        int b = n >> 10, p = n & 1023, y = p >> 5, x = p & 31;
        const float* ib = inp + (size_t)b * (128 * 32 * 32);
        const float* wp = weight + (size_t)m * 1152;
        float s = 0.0f;
        int d = r * 64;
        for (int c = 0; c < 64; ++c, ++d) {
            int ci = d / 9, rem = d - ci * 9;
            int kh = rem / 3, kw = rem - kh * 3;
            int yy = y + kh - 1, xx = x + kw - 1;
            float xv = 0.0f;
            if ((unsigned)yy < 32u && (unsigned)xx < 32u)
                xv = ib[(ci * 32 + yy) * 32 + xx];
            float q = rintf(__fmul_rn(wp[d], sc));
            q = fminf(fmaxf(q, -7.0f), 7.0f);
            s = __fadd_rn(s, __fmul_rn(xv, q));
        }
        int nb = (s >= 0.0f) ? 1 : 0;
        if (nb != bit)
            atomicAdd(&out[(((size_t)(b * 256 + m)) << 10) + p], nb ? 1.0f : -1.0f);
    }
}

extern "C" void kernel_launch(void* const* d_in, const int* in_sizes, int n_in,
                              void* d_out, int out_size, void* d_ws, size_t ws_size,
                              hipStream_t stream) {
    const float* inp    = (const float*)d_in[0];   // [16,128,32,32]
    const float* weight = (const float*)d_in[1];   // [256,128,3,3]
    float* out = (float*)d_out;                    // [16,256,32,32]

    char* ws = (char*)d_ws;
    float*    pmin  = (float*)(ws + 0);
    float*    pmax  = (float*)(ws + 256);
    unsigned* cnt   = (unsigned*)(ws + 516);
    uv4*      wqb   = (uv4*)(ws + 1024);          // 589,824 B
    unsigned* xpk   = (unsigned*)(ws + 590848);   // 9,469,952 B
    unsigned* list  = (unsigned*)(ws + 10060800); // up to 1 MB

    size_t avail = (ws_size > 10060800) ? (ws_size - 10060800) / 4 : 0;
    int cap = (int)(avail < CAP_MAX ? avail : CAP_MAX);

    k_minmax<<<64, 256, 0, stream>>>(weight, pmin, pmax, cnt);
    k_quantb<<<144, 256, 0, stream>>>(weight, pmin, pmax, wqb);
    k_pad<<<2048, 256, 0, stream>>>(inp, xpk);

    dim3 grid(256, 4);   // (N/64, M/64)
    k_main<<<grid, 256, 0, stream>>>(xpk, wqb, out, cnt, list, cap);
    k_fix<<<64, 256, 0, stream>>>(inp, weight, pmin, pmax, cnt, list, out, cap);
}

// Round 6
// 149.772 us; speedup vs baseline: 5.2639x; 1.4184x over previous
//
#include <hip/hip_runtime.h>

// ONN conv2d: B=16, Cin=128, H=W=32, Cout=256, k=3 (pad=1, stride=1)
// N=16384 positions, D=1152=18*64 chunks of VEC=64, M=256.
// out[n,m] = sum_r sign01( dot_c( x[n,64r+c], wq[64r+c,m] ) )
// wq = clamp(rintf(w*scale), -7, 7), scale = fl32(15/(fl32(max-min)+1e-9f))
//
// Main path: bf16 MFMA with x split hi/lo (w int4 exact in bf16).
// |mfma_dot - ref_fp32_chain| < ~2e-3; dots with |s| < TAU=0.03 are recomputed
// bit-exactly (sequential fp32, ascending c, separate mul/add) by k_fix.
// R3->R4: per-dot global atomics -> per-block LDS queue (611 -> <93 us k_main).
// R5 FAILED (absmax 1.0): unrolled k_fix body (xv[64]/wv[64] + carry-chain ifs)
//   flipped one sign -- reverted to the R4 body verbatim (proven absmax 0.0).
// R6: ONLY change vs R4 = k_fix grid 64 -> 512 (R4 showed 2.1% occupancy,
//   3 serial hits/thread; grid size cannot affect numerics).

#define TAU 0.03f
#define CAP_MAX 262144
#define HITCAP 2048

typedef short short8 __attribute__((ext_vector_type(8)));
typedef float f32x4 __attribute__((ext_vector_type(4)));
typedef unsigned int uv4u __attribute__((ext_vector_type(4), aligned(4)));   // unaligned-ok loads
typedef unsigned int uv4 __attribute__((ext_vector_type(4)));                // 16B-aligned
typedef unsigned int uv2 __attribute__((ext_vector_type(2)));

__device__ __forceinline__ unsigned short bf16rn(float v) {
    unsigned u = __float_as_uint(v);
    unsigned r = u + 0x7fffu + ((u >> 16) & 1u);
    return (unsigned short)(r >> 16);
}

// ---------------- prep: weight min/max partials ----------------
__global__ __launch_bounds__(256) void k_minmax(const float* __restrict__ w,
                                                float* __restrict__ pmin,
                                                float* __restrict__ pmax,
                                                unsigned* __restrict__ cnt) {
    if (blockIdx.x == 0 && threadIdx.x == 0) *cnt = 0u;
    int tid = blockIdx.x * blockDim.x + threadIdx.x;
    float vmin = 1e30f, vmax = -1e30f;
    for (int i = tid; i < 294912; i += gridDim.x * blockDim.x) {
        float v = w[i];
        vmin = fminf(vmin, v);
        vmax = fmaxf(vmax, v);
    }
    #pragma unroll
    for (int off = 32; off > 0; off >>= 1) {
        vmin = fminf(vmin, __shfl_down(vmin, off, 64));
        vmax = fmaxf(vmax, __shfl_down(vmax, off, 64));
    }
    __shared__ float smin[4], smax[4];
    int wave = threadIdx.x >> 6;
    if ((threadIdx.x & 63) == 0) { smin[wave] = vmin; smax[wave] = vmax; }
    __syncthreads();
    if (threadIdx.x == 0) {
        #pragma unroll
        for (int i = 1; i < 4; i++) {
            vmin = fminf(vmin, smin[i]);
            vmax = fmaxf(vmax, smax[i]);
        }
        pmin[blockIdx.x] = vmin;
        pmax[blockIdx.x] = vmax;
    }
}

// block-local scale from the 64 partials (identical fp32 op sequence everywhere)
__device__ __forceinline__ float block_scale(const float* pmin, const float* pmax,
                                             float* sca_lds) {
    int t = threadIdx.x;
    if (t < 64) {
        float vmin = pmin[t];
        float vmax = pmax[t];
        #pragma unroll
        for (int off = 32; off > 0; off >>= 1) {
            vmin = fminf(vmin, __shfl_down(vmin, off, 64));
            vmax = fmaxf(vmax, __shfl_down(vmax, off, 64));
        }
        if (t == 0) {
            float tt = __fadd_rn(__fsub_rn(vmax, vmin), 1e-9f);
            *sca_lds = __fdiv_rn(15.0f, tt);
        }
    }
    __syncthreads();
    return *sca_lds;
}

// ---------------- prep: quantize weights into MFMA A-fragment order ----------------
// slot = ((g*18 + r)*8 + mt*2 + khalf)*64 + lane ; 16B per slot (8 bf16, k ascending)
// value(lane, j) = wq[d = 64r + khalf*32 + (lane>>4)*8 + j][m = g*64 + mt*16 + (lane&15)]
__global__ __launch_bounds__(256) void k_quantb(const float* __restrict__ w,
                                                const float* __restrict__ pmin,
                                                const float* __restrict__ pmax,
                                                uv4* __restrict__ wqb) {
    __shared__ float sca;
    float s = block_scale(pmin, pmax, &sca);
    int slot = blockIdx.x * 256 + threadIdx.x;   // 36864 total
    int lane = slot & 63;
    int sub = slot >> 6;
    int khalf = sub & 1;
    int mt = (sub >> 1) & 3;
    int gr = sub >> 3;                 // g*18 + r
    int g = gr / 18, r = gr - g * 18;
    int m = g * 64 + mt * 16 + (lane & 15);
    int dbase = r * 64 + khalf * 32 + (lane >> 4) * 8;
    const float* wp = w + (size_t)m * 1152 + dbase;
    unsigned o[4];
    #pragma unroll
    for (int p = 0; p < 4; ++p) {
        float q0 = rintf(__fmul_rn(wp[2 * p], s));
        float q1 = rintf(__fmul_rn(wp[2 * p + 1], s));
        q0 = fminf(fmaxf(q0, -7.0f), 7.0f);
        q1 = fminf(fmaxf(q1, -7.0f), 7.0f);
        o[p] = (unsigned)bf16rn(q0) | ((unsigned)bf16rn(q1) << 16);
    }
    uv4 v; v.x = o[0]; v.y = o[1]; v.z = o[2]; v.w = o[3];
    wqb[slot] = v;
}

// ---------------- prep: zero-padded hi/lo bf16 planes ----------------
// xpk[bc][yy][xx], yy,xx in [0,34), u32 = lo16<<16 | hi16, zero halo
__global__ __launch_bounds__(256) void k_pad(const float* __restrict__ inp,
                                             unsigned* __restrict__ xpk) {
    int bc = blockIdx.x;                       // b*128 + cin (2048)
    const float* src = inp + (size_t)bc * 1024;
    unsigned* dst = xpk + (size_t)bc * 1156;
    #pragma unroll
    for (int i = 0; i < 5; ++i) {
        int idx = threadIdx.x + i * 256;
        if (idx < 1156) {
            int yy = idx / 34, xx = idx - yy * 34;
            float v = 0.0f;
            int ys = yy - 1, xs_ = xx - 1;
            if ((unsigned)ys < 32u && (unsigned)xs_ < 32u) v = src[ys * 32 + xs_];
            unsigned short h = bf16rn(v);
            float hf = __uint_as_float((unsigned)h << 16);
            unsigned short l = bf16rn(v - hf);
            dst[idx] = (unsigned)h | ((unsigned)l << 16);
        }
    }
}

// ---------------- main: MFMA GEMM-sign ----------------
__global__ __launch_bounds__(256) void k_main(const unsigned* __restrict__ xpk,
                                              const uv4* __restrict__ wqb,
                                              float* __restrict__ out,
                                              unsigned* __restrict__ cnt,
                                              unsigned* __restrict__ list,
                                              int cap) {
    __shared__ unsigned xs[64 * 66];   // [k][n] packed hi|lo, stride 66 (2-way banks)
    __shared__ uv4 asld[512];          // A frags for this chunk (8 KB)
    __shared__ unsigned hitbuf[HITCAP];
    __shared__ unsigned hitcnt, hitbase;

    const int t = threadIdx.x;
    const int lane = t & 63;
    const int wv = t >> 6;             // wave id = n-tile
    const int quad = lane >> 4;
    const int nl = lane & 15;
    const int n0 = blockIdx.x * 64;
    const int g = blockIdx.y;
    const int b = n0 >> 10;

    if (t == 0) hitcnt = 0u;

    // staging mapping: thread -> (k row, 16-n segment)
    const int sk = t >> 2;
    const int sseg = t & 3;
    const int sy = ((n0 & 1023) >> 5) + (sseg >> 1);  // image row (0..31)
    const int sx0 = (sseg & 1) * 16;
    int cin = sk / 9;
    int rem9 = sk - cin * 9;
    const unsigned* xbase = xpk + (size_t)b * (128 * 1156);

    int counts[4][4] = {};
    const int aslotbase = g * 18 * 512;

    for (int r = 0; r < 18; ++r) {
        // ---- stage A frags (global, already frag-ordered) ----
        asld[t] = wqb[aslotbase + r * 512 + t];
        asld[t + 256] = wqb[aslotbase + r * 512 + t + 256];
        // ---- stage X tile: 16 contiguous u32 from padded plane row ----
        {
            int kh = rem9 / 3;
            int kw = rem9 - kh * 3;
            const unsigned* srow = xbase + cin * 1156 + (sy + kh) * 34 + kw + sx0;
            uv4u v0 = *(const uv4u*)(srow + 0);
            uv4u v1 = *(const uv4u*)(srow + 4);
            uv4u v2 = *(const uv4u*)(srow + 8);
            uv4u v3 = *(const uv4u*)(srow + 12);
            uv2* d2 = (uv2*)&xs[sk * 66 + sseg * 16];
            uv2 w0; w0.x = v0.x; w0.y = v0.y; d2[0] = w0;
            uv2 w1; w1.x = v0.z; w1.y = v0.w; d2[1] = w1;
            uv2 w2; w2.x = v1.x; w2.y = v1.y; d2[2] = w2;
            uv2 w3; w3.x = v1.z; w3.y = v1.w; d2[3] = w3;
            uv2 w4; w4.x = v2.x; w4.y = v2.y; d2[4] = w4;
            uv2 w5; w5.x = v2.z; w5.y = v2.w; d2[5] = w5;
            uv2 w6; w6.x = v3.x; w6.y = v3.y; d2[6] = w6;
            uv2 w7; w7.x = v3.z; w7.y = v3.w; d2[7] = w7;
        }
        // incremental d += 64 decode state (64 = 7*9 + 1)
        rem9 += 1;
        if (rem9 == 9) { rem9 = 0; cin += 8; } else { cin += 7; }

        __syncthreads();

        // ---- A fragments ----
        short8 af[4][2];
        #pragma unroll
        for (int mt = 0; mt < 4; ++mt)
            #pragma unroll
            for (int kh2 = 0; kh2 < 2; ++kh2) {
                uv4 u = asld[(mt * 2 + kh2) * 64 + lane];
                af[mt][kh2] = __builtin_bit_cast(short8, u);
            }

        // ---- B fragments (split packed hi|lo) ----
        short8 bhi[2], blo[2];
        {
            const int base = quad * 8 * 66 + wv * 16 + nl;
            #pragma unroll
            for (int kh2 = 0; kh2 < 2; ++kh2) {
                unsigned u[8];
                #pragma unroll
                for (int j = 0; j < 8; ++j)
                    u[j] = xs[base + (kh2 * 32 + j) * 66];
                union { unsigned d[4]; short8 v; } H, L;
                #pragma unroll
                for (int p = 0; p < 4; ++p) {
                    unsigned ua = u[2 * p], ub = u[2 * p + 1];
                    H.d[p] = (ua & 0xffffu) | (ub << 16);
                    L.d[p] = (ua >> 16) | (ub & 0xffff0000u);
                }
                bhi[kh2] = H.v;
                blo[kh2] = L.v;
            }
        }

        // ---- MFMA per m-tile, binarize, borderline -> LDS queue ----
        #pragma unroll
        for (int mt = 0; mt < 4; ++mt) {
            f32x4 acc = {0.0f, 0.0f, 0.0f, 0.0f};
            acc = __builtin_amdgcn_mfma_f32_16x16x32_bf16(af[mt][0], bhi[0], acc, 0, 0, 0);
            acc = __builtin_amdgcn_mfma_f32_16x16x32_bf16(af[mt][1], bhi[1], acc, 0, 0, 0);
            acc = __builtin_amdgcn_mfma_f32_16x16x32_bf16(af[mt][0], blo[0], acc, 0, 0, 0);
            acc = __builtin_amdgcn_mfma_f32_16x16x32_bf16(af[mt][1], blo[1], acc, 0, 0, 0);
            #pragma unroll
            for (int i = 0; i < 4; ++i) {
                float s = acc[i];
                int ge = (s >= 0.0f) ? 1 : 0;
                counts[mt][i] += ge;
                if (__builtin_fabsf(s) < TAU) {
                    unsigned idx = atomicAdd(&hitcnt, 1u);   // LDS atomic: fast
                    if (idx < (unsigned)HITCAP) {
                        unsigned m = (unsigned)(g * 64 + mt * 16 + quad * 4 + i);
                        unsigned n = (unsigned)(n0 + wv * 16 + nl);
                        hitbuf[idx] = n | ((unsigned)r << 14) | (m << 19) | ((unsigned)ge << 27);
                    }
                }
            }
        }
        __syncthreads();
    }

    // ---- epilogue: C/D layout col=lane&15 (n), row=quad*4+reg (m) ----
    const int n = n0 + wv * 16 + nl;
    const int p = n & 1023;
    #pragma unroll
    for (int mt = 0; mt < 4; ++mt)
        #pragma unroll
        for (int i = 0; i < 4; ++i) {
            int m = g * 64 + mt * 16 + quad * 4 + i;
            out[(((size_t)(b * 256 + m)) << 10) + p] = (float)counts[mt][i];
        }

    // ---- flush LDS hit queue: ONE global atomic per block + coalesced dump ----
    unsigned tot = hitcnt;
    if (tot > (unsigned)HITCAP) tot = (unsigned)HITCAP;
    if (t == 0) hitbase = atomicAdd(cnt, tot);
    __syncthreads();
    unsigned base = hitbase;
    for (unsigned i = t; i < tot; i += 256)
        if (base + i < (unsigned)cap) list[base + i] = hitbuf[i];
}

// ---------------- fixup: bit-exact recompute of borderline dots ----------------
// R4 body VERBATIM (proven absmax 0.0). Only the grid changed (64 -> 512).
__global__ __launch_bounds__(256) void k_fix(const float* __restrict__ inp,
                                             const float* __restrict__ weight,
                                             const float* __restrict__ pmin,
                                             const float* __restrict__ pmax,
                                             const unsigned* __restrict__ cnt,
                                             const unsigned* __restrict__ list,
                                             float* __restrict__ out, int cap) {
    __shared__ float sca;
    float sc = block_scale(pmin, pmax, &sca);
    unsigned total = *cnt;
    if (total > (unsigned)cap) total = (unsigned)cap;
    for (unsigned i = blockIdx.x * 256 + threadIdx.x; i < total; i += gridDim.x * 256) {
        unsigned u = list[i];
        int n = u & 16383;
        int r = (u >> 14) & 31;
        int m = (u >> 19) & 255;
        int bit = (u >> 27) & 1;
        int b = n >> 10, p = n & 1023, y = p >> 5, x = p & 31;
        const float* ib = inp + (size_t)b * (128 * 32 * 32);
        const float* wp = weight + (size_t)m * 1152;
        float s = 0.0f;
        int d = r * 64;
        for (int c = 0; c < 64; ++c, ++d) {
            int ci = d / 9, rem = d - ci * 9;
            int kh = rem / 3, kw = rem - kh * 3;
            int yy = y + kh - 1, xx = x + kw - 1;
            float xv = 0.0f;
            if ((unsigned)yy < 32u && (unsigned)xx < 32u)
                xv = ib[(ci * 32 + yy) * 32 + xx];
            float q = rintf(__fmul_rn(wp[d], sc));
            q = fminf(fmaxf(q, -7.0f), 7.0f);
            s = __fadd_rn(s, __fmul_rn(xv, q));
        }
        int nb = (s >= 0.0f) ? 1 : 0;
        if (nb != bit)
            atomicAdd(&out[(((size_t)(b * 256 + m)) << 10) + p], nb ? 1.0f : -1.0f);
    }
}

extern "C" void kernel_launch(void* const* d_in, const int* in_sizes, int n_in,
                              void* d_out, int out_size, void* d_ws, size_t ws_size,
                              hipStream_t stream) {
    const float* inp    = (const float*)d_in[0];   // [16,128,32,32]
    const float* weight = (const float*)d_in[1];   // [256,128,3,3]
    float* out = (float*)d_out;                    // [16,256,32,32]

    char* ws = (char*)d_ws;
    float*    pmin  = (float*)(ws + 0);
    float*    pmax  = (float*)(ws + 256);
    unsigned* cnt   = (unsigned*)(ws + 516);
    uv4*      wqb   = (uv4*)(ws + 1024);          // 589,824 B
    unsigned* xpk   = (unsigned*)(ws + 590848);   // 9,469,952 B
    unsigned* list  = (unsigned*)(ws + 10060800); // up to 1 MB

    size_t avail = (ws_size > 10060800) ? (ws_size - 10060800) / 4 : 0;
    int cap = (int)(avail < CAP_MAX ? avail : CAP_MAX);

    k_minmax<<<64, 256, 0, stream>>>(weight, pmin, pmax, cnt);
    k_quantb<<<144, 256, 0, stream>>>(weight, pmin, pmax, wqb);
    k_pad<<<2048, 256, 0, stream>>>(inp, xpk);

    dim3 grid(256, 4);   // (N/64, M/64)
    k_main<<<grid, 256, 0, stream>>>(xpk, wqb, out, cnt, list, cap);
    k_fix<<<512, 256, 0, stream>>>(inp, weight, pmin, pmax, cnt, list, out, cap);
}

// Round 7
// 149.193 us; speedup vs baseline: 5.2843x; 1.0039x over previous
//
#include <hip/hip_runtime.h>

// ONN conv2d: B=16, Cin=128, H=W=32, Cout=256, k=3 (pad=1, stride=1)
// N=16384 positions, D=1152=18*64 chunks of VEC=64, M=256.
// out[n,m] = sum_r sign01( dot_c( x[n,64r+c], wq[64r+c,m] ) )
// wq = clamp(rintf(w*scale), -7, 7), scale = fl32(15/(fl32(max-min)+1e-9f))
//
// Main path: bf16 MFMA with x split hi/lo (w int4 exact in bf16).
// |mfma_dot - ref_fp32_chain| < ~2e-3; dots with |s| < TAU=0.03 are recomputed
// bit-exactly (sequential fp32, ascending c, separate mul/add) by k_fix.
// R3->R4: per-dot global atomics -> per-block LDS queue (611 -> 93 us).
// R5 FAILED: rewritten k_fix body flipped a sign; reverted to R4 body (proven).
// R6: k_fix grid 64->512 (93 -> <55 us). Total 149.8, k_main 55 us at
//     MfmaUtil 12.7 / VALUBusy 31 / occ 33% -- barrier+latency bound.
// R7: k_main v2 = BARRIER-FREE gather GEMM. No LDS tiles: B-frag u32s
//     gathered straight from padded planes (L2-resident), A-frags straight
//     from frag-ordered wqb. Same element values, same MFMA order as R6.
//     Also merged k_minmax+k_pad into k_prep (one fewer launch).

#define TAU 0.03f
#define CAP_MAX 262144
#define HITCAP 2048

typedef short short8 __attribute__((ext_vector_type(8)));
typedef float f32x4 __attribute__((ext_vector_type(4)));
typedef unsigned int uv4 __attribute__((ext_vector_type(4)));
typedef unsigned int uv2 __attribute__((ext_vector_type(2)));

__device__ __forceinline__ unsigned short bf16rn(float v) {
    unsigned u = __float_as_uint(v);
    unsigned r = u + 0x7fffu + ((u >> 16) & 1u);
    return (unsigned short)(r >> 16);
}

// ---------------- prep: weight min/max partials (blocks 0..63) +
//                  zero-padded hi/lo bf16 planes (blocks 64..2111) ----------------
__global__ __launch_bounds__(256) void k_prep(const float* __restrict__ w,
                                              const float* __restrict__ inp,
                                              float* __restrict__ pmin,
                                              float* __restrict__ pmax,
                                              unsigned* __restrict__ cnt,
                                              unsigned* __restrict__ xpk) {
    if (blockIdx.x < 64) {
        if (blockIdx.x == 0 && threadIdx.x == 0) *cnt = 0u;
        int tid = blockIdx.x * 256 + threadIdx.x;
        float vmin = 1e30f, vmax = -1e30f;
        for (int i = tid; i < 294912; i += 64 * 256) {
            float v = w[i];
            vmin = fminf(vmin, v);
            vmax = fmaxf(vmax, v);
        }
        #pragma unroll
        for (int off = 32; off > 0; off >>= 1) {
            vmin = fminf(vmin, __shfl_down(vmin, off, 64));
            vmax = fmaxf(vmax, __shfl_down(vmax, off, 64));
        }
        __shared__ float smin[4], smax[4];
        int wave = threadIdx.x >> 6;
        if ((threadIdx.x & 63) == 0) { smin[wave] = vmin; smax[wave] = vmax; }
        __syncthreads();
        if (threadIdx.x == 0) {
            #pragma unroll
            for (int i = 1; i < 4; i++) {
                vmin = fminf(vmin, smin[i]);
                vmax = fmaxf(vmax, smax[i]);
            }
            pmin[blockIdx.x] = vmin;
            pmax[blockIdx.x] = vmax;
        }
    } else {
        int bc = blockIdx.x - 64;              // b*128 + cin (2048)
        const float* src = inp + (size_t)bc * 1024;
        unsigned* dst = xpk + (size_t)bc * 1156;
        #pragma unroll
        for (int i = 0; i < 5; ++i) {
            int idx = threadIdx.x + i * 256;
            if (idx < 1156) {
                int yy = idx / 34, xx = idx - yy * 34;
                float v = 0.0f;
                int ys = yy - 1, xs_ = xx - 1;
                if ((unsigned)ys < 32u && (unsigned)xs_ < 32u) v = src[ys * 32 + xs_];
                unsigned short h = bf16rn(v);
                float hf = __uint_as_float((unsigned)h << 16);
                unsigned short l = bf16rn(v - hf);
                dst[idx] = (unsigned)h | ((unsigned)l << 16);
            }
        }
    }
}

// block-local scale from the 64 partials (identical fp32 op sequence everywhere)
__device__ __forceinline__ float block_scale(const float* pmin, const float* pmax,
                                             float* sca_lds) {
    int t = threadIdx.x;
    if (t < 64) {
        float vmin = pmin[t];
        float vmax = pmax[t];
        #pragma unroll
        for (int off = 32; off > 0; off >>= 1) {
            vmin = fminf(vmin, __shfl_down(vmin, off, 64));
            vmax = fmaxf(vmax, __shfl_down(vmax, off, 64));
        }
        if (t == 0) {
            float tt = __fadd_rn(__fsub_rn(vmax, vmin), 1e-9f);
            *sca_lds = __fdiv_rn(15.0f, tt);
        }
    }
    __syncthreads();
    return *sca_lds;
}

// ---------------- prep: quantize weights into MFMA A-fragment order ----------------
// slot = ((g*18 + r)*8 + mt*2 + khalf)*64 + lane ; 16B per slot (8 bf16, k ascending)
// value(lane, j) = wq[d = 64r + khalf*32 + (lane>>4)*8 + j][m = g*64 + mt*16 + (lane&15)]
__global__ __launch_bounds__(256) void k_quantb(const float* __restrict__ w,
                                                const float* __restrict__ pmin,
                                                const float* __restrict__ pmax,
                                                uv4* __restrict__ wqb) {
    __shared__ float sca;
    float s = block_scale(pmin, pmax, &sca);
    int slot = blockIdx.x * 256 + threadIdx.x;   // 36864 total
    int lane = slot & 63;
    int sub = slot >> 6;
    int khalf = sub & 1;
    int mt = (sub >> 1) & 3;
    int gr = sub >> 3;                 // g*18 + r
    int g = gr / 18, r = gr - g * 18;
    int m = g * 64 + mt * 16 + (lane & 15);
    int dbase = r * 64 + khalf * 32 + (lane >> 4) * 8;
    const float* wp = w + (size_t)m * 1152 + dbase;
    unsigned o[4];
    #pragma unroll
    for (int p = 0; p < 4; ++p) {
        float q0 = rintf(__fmul_rn(wp[2 * p], s));
        float q1 = rintf(__fmul_rn(wp[2 * p + 1], s));
        q0 = fminf(fmaxf(q0, -7.0f), 7.0f);
        q1 = fminf(fmaxf(q1, -7.0f), 7.0f);
        o[p] = (unsigned)bf16rn(q0) | ((unsigned)bf16rn(q1) << 16);
    }
    uv4 v; v.x = o[0]; v.y = o[1]; v.z = o[2]; v.w = o[3];
    wqb[slot] = v;
}

// ---------------- main: barrier-free MFMA gather-GEMM ----------------
// Wave = 16n x 64m tile; B-frag u32s gathered from xpk (16 x 4B, quad-segment
// coalesced), A-frags loaded from wqb (8 x 16B, lane-coalesced). Plane offsets
// for each k come from a per-block LDS table (1 broadcast read + 1 add).
__global__ __launch_bounds__(256) void k_main(const unsigned* __restrict__ xpk,
                                              const uv4* __restrict__ wqb,
                                              float* __restrict__ out,
                                              unsigned* __restrict__ cnt,
                                              unsigned* __restrict__ list,
                                              int cap) {
    __shared__ int ofs_s[1152];        // plane offset for each k: cin*1156+kh*34+kw
    __shared__ unsigned hitbuf[HITCAP];
    __shared__ unsigned hitcnt, hitbase;

    const int t = threadIdx.x;
    if (t == 0) hitcnt = 0u;
    for (int k = t; k < 1152; k += 256) {
        int cin = k / 9;
        int rem = k - cin * 9;
        int kh = rem / 3;
        int kw = rem - kh * 3;
        ofs_s[k] = cin * 1156 + kh * 34 + kw;
    }
    __syncthreads();

    const int lane = t & 63;
    const int wv = t >> 6;             // wave id = n-tile
    const int quad = lane >> 4;
    const int nl = lane & 15;
    const int n0 = blockIdx.x * 64;
    const int g = blockIdx.y;
    const int b = n0 >> 10;

    // wave's image-position base (16 consecutive positions within one row)
    const int sy_w = ((n0 & 1023) >> 5) + (wv >> 1);
    const int col0 = (wv & 1) * 16;
    const unsigned* __restrict__ xw =
        xpk + (size_t)b * (128 * 1156) + sy_w * 34 + col0 + nl;
    const uv4* __restrict__ aw = wqb + (size_t)g * (18 * 512) + lane;

    int counts[4][4] = {};

    for (int r = 0; r < 18; ++r) {
        // ---- B fragments: gather 16 u32 (hi|lo packed) from padded planes ----
        short8 bhi[2], blo[2];
        #pragma unroll
        for (int kh2 = 0; kh2 < 2; ++kh2) {
            unsigned u[8];
            #pragma unroll
            for (int j = 0; j < 8; ++j) {
                int k = r * 64 + kh2 * 32 + quad * 8 + j;
                u[j] = xw[ofs_s[k]];
            }
            union { unsigned d[4]; short8 v; } H, L;
            #pragma unroll
            for (int p = 0; p < 4; ++p) {
                unsigned ua = u[2 * p], ub = u[2 * p + 1];
                H.d[p] = (ua & 0xffffu) | (ub << 16);
                L.d[p] = (ua >> 16) | (ub & 0xffff0000u);
            }
            bhi[kh2] = H.v;
            blo[kh2] = L.v;
        }

        // ---- per m-tile: A frags direct from global, 4 MFMAs, checks ----
        #pragma unroll
        for (int mt = 0; mt < 4; ++mt) {
            short8 af0 = __builtin_bit_cast(short8, aw[r * 512 + (mt * 2 + 0) * 64]);
            short8 af1 = __builtin_bit_cast(short8, aw[r * 512 + (mt * 2 + 1) * 64]);
            f32x4 acc = {0.0f, 0.0f, 0.0f, 0.0f};
            acc = __builtin_amdgcn_mfma_f32_16x16x32_bf16(af0, bhi[0], acc, 0, 0, 0);
            acc = __builtin_amdgcn_mfma_f32_16x16x32_bf16(af1, bhi[1], acc, 0, 0, 0);
            acc = __builtin_amdgcn_mfma_f32_16x16x32_bf16(af0, blo[0], acc, 0, 0, 0);
            acc = __builtin_amdgcn_mfma_f32_16x16x32_bf16(af1, blo[1], acc, 0, 0, 0);
            #pragma unroll
            for (int i = 0; i < 4; ++i) {
                float s = acc[i];
                int ge = (s >= 0.0f) ? 1 : 0;
                counts[mt][i] += ge;
                if (__builtin_fabsf(s) < TAU) {
                    unsigned idx = atomicAdd(&hitcnt, 1u);   // LDS atomic: fast, rare
                    if (idx < (unsigned)HITCAP) {
                        unsigned m = (unsigned)(g * 64 + mt * 16 + quad * 4 + i);
                        unsigned n = (unsigned)(n0 + wv * 16 + nl);
                        hitbuf[idx] = n | ((unsigned)r << 14) | (m << 19) | ((unsigned)ge << 27);
                    }
                }
            }
        }
    }

    // ---- epilogue: C/D layout col=lane&15 (n), row=quad*4+reg (m) ----
    const int n = n0 + wv * 16 + nl;
    const int p = n & 1023;
    #pragma unroll
    for (int mt = 0; mt < 4; ++mt)
        #pragma unroll
        for (int i = 0; i < 4; ++i) {
            int m = g * 64 + mt * 16 + quad * 4 + i;
            out[(((size_t)(b * 256 + m)) << 10) + p] = (float)counts[mt][i];
        }

    // ---- flush LDS hit queue: ONE global atomic per block + coalesced dump ----
    __syncthreads();
    unsigned tot = hitcnt;
    if (tot > (unsigned)HITCAP) tot = (unsigned)HITCAP;
    if (t == 0) hitbase = atomicAdd(cnt, tot);
    __syncthreads();
    unsigned base = hitbase;
    for (unsigned i = t; i < tot; i += 256)
        if (base + i < (unsigned)cap) list[base + i] = hitbuf[i];
}

// ---------------- fixup: bit-exact recompute of borderline dots ----------------
// R4 body VERBATIM (proven absmax 0.0), 512 blocks (proven R6).
__global__ __launch_bounds__(256) void k_fix(const float* __restrict__ inp,
                                             const float* __restrict__ weight,
                                             const float* __restrict__ pmin,
                                             const float* __restrict__ pmax,
                                             const unsigned* __restrict__ cnt,
                                             const unsigned* __restrict__ list,
                                             float* __restrict__ out, int cap) {
    __shared__ float sca;
    float sc = block_scale(pmin, pmax, &sca);
    unsigned total = *cnt;
    if (total > (unsigned)cap) total = (unsigned)cap;
    for (unsigned i = blockIdx.x * 256 + threadIdx.x; i < total; i += gridDim.x * 256) {
        unsigned u = list[i];
        int n = u & 16383;
        int r = (u >> 14) & 31;
        int m = (u >> 19) & 255;
        int bit = (u >> 27) & 1;
        int b = n >> 10, p = n & 1023, y = p >> 5, x = p & 31;
        const float* ib = inp + (size_t)b * (128 * 32 * 32);
        const float* wp = weight + (size_t)m * 1152;
        float s = 0.0f;
        int d = r * 64;
        for (int c = 0; c < 64; ++c, ++d) {
            int ci = d / 9, rem = d - ci * 9;
            int kh = rem / 3, kw = rem - kh * 3;
            int yy = y + kh - 1, xx = x + kw - 1;
            float xv = 0.0f;
            if ((unsigned)yy < 32u && (unsigned)xx < 32u)
                xv = ib[(ci * 32 + yy) * 32 + xx];
            float q = rintf(__fmul_rn(wp[d], sc));
            q = fminf(fmaxf(q, -7.0f), 7.0f);
            s = __fadd_rn(s, __fmul_rn(xv, q));
        }
        int nb = (s >= 0.0f) ? 1 : 0;
        if (nb != bit)
            atomicAdd(&out[(((size_t)(b * 256 + m)) << 10) + p], nb ? 1.0f : -1.0f);
    }
}

extern "C" void kernel_launch(void* const* d_in, const int* in_sizes, int n_in,
                              void* d_out, int out_size, void* d_ws, size_t ws_size,
                              hipStream_t stream) {
    const float* inp    = (const float*)d_in[0];   // [16,128,32,32]
    const float* weight = (const float*)d_in[1];   // [256,128,3,3]
    float* out = (float*)d_out;                    // [16,256,32,32]

    char* ws = (char*)d_ws;
    float*    pmin  = (float*)(ws + 0);
    float*    pmax  = (float*)(ws + 256);
    unsigned* cnt   = (unsigned*)(ws + 516);
    uv4*      wqb   = (uv4*)(ws + 1024);          // 589,824 B
    unsigned* xpk   = (unsigned*)(ws + 590848);   // 9,469,952 B
    unsigned* list  = (unsigned*)(ws + 10060800); // up to 1 MB

    size_t avail = (ws_size > 10060800) ? (ws_size - 10060800) / 4 : 0;
    int cap = (int)(avail < CAP_MAX ? avail : CAP_MAX);

    k_prep<<<2112, 256, 0, stream>>>(weight, inp, pmin, pmax, cnt, xpk);
    k_quantb<<<144, 256, 0, stream>>>(weight, pmin, pmax, wqb);

    dim3 grid(256, 4);   // (N/64, M/64)
    k_main<<<grid, 256, 0, stream>>>(xpk, wqb, out, cnt, list, cap);
    k_fix<<<512, 256, 0, stream>>>(inp, weight, pmin, pmax, cnt, list, out, cap);
}

// Round 8
// 130.765 us; speedup vs baseline: 6.0290x; 1.1409x over previous
//
#include <hip/hip_runtime.h>

// ONN conv2d: B=16, Cin=128, H=W=32, Cout=256, k=3 (pad=1, stride=1)
// N=16384 positions, D=1152=18*64 chunks of VEC=64, M=256.
// out[n,m] = sum_r sign01( dot_c( x[n,64r+c], wq[64r+c,m] ) )
// wq = clamp(rintf(w*scale), -7, 7), scale = fl32(15/(fl32(max-min)+1e-9f))
//
// Main path: bf16 MFMA with x split hi/lo (w int4 exact in bf16).
// |mfma_dot - ref_fp32_chain| < ~2e-3; dots with |s| < TAU=0.03 recomputed
// bit-exactly (sequential fp32, ascending c, separate mul/add -- R4 body).
// R3->R4: per-dot global atomics -> per-block LDS queue (611 -> 93 us).
// R5 FAILED: rewritten k_fix body flipped a sign; reverted (proven R4 body).
// R6: k_fix grid 64->512. R7: barrier-free gather k_main (53.8 us,
//     MfmaUtil 13 / VALUBusy 40 -- L2-gather latency unhidden).
// R8: (a) depth-1 register prefetch of next chunk's B-gather u32s;
//     (b) k_fix folded into k_main tail (block fixes its own hits,
//     R4 fix body verbatim) -- one fewer launch, no global list.

#define TAU 0.03f
#define HITCAP 2048

typedef short short8 __attribute__((ext_vector_type(8)));
typedef float f32x4 __attribute__((ext_vector_type(4)));
typedef unsigned int uv4 __attribute__((ext_vector_type(4)));

__device__ __forceinline__ unsigned short bf16rn(float v) {
    unsigned u = __float_as_uint(v);
    unsigned r = u + 0x7fffu + ((u >> 16) & 1u);
    return (unsigned short)(r >> 16);
}

// ---------------- prep: weight min/max partials (blocks 0..63) +
//                  zero-padded hi/lo bf16 planes (blocks 64..2111) ----------------
__global__ __launch_bounds__(256) void k_prep(const float* __restrict__ w,
                                              const float* __restrict__ inp,
                                              float* __restrict__ pmin,
                                              float* __restrict__ pmax,
                                              unsigned* __restrict__ xpk) {
    if (blockIdx.x < 64) {
        int tid = blockIdx.x * 256 + threadIdx.x;
        float vmin = 1e30f, vmax = -1e30f;
        for (int i = tid; i < 294912; i += 64 * 256) {
            float v = w[i];
            vmin = fminf(vmin, v);
            vmax = fmaxf(vmax, v);
        }
        #pragma unroll
        for (int off = 32; off > 0; off >>= 1) {
            vmin = fminf(vmin, __shfl_down(vmin, off, 64));
            vmax = fmaxf(vmax, __shfl_down(vmax, off, 64));
        }
        __shared__ float smin[4], smax[4];
        int wave = threadIdx.x >> 6;
        if ((threadIdx.x & 63) == 0) { smin[wave] = vmin; smax[wave] = vmax; }
        __syncthreads();
        if (threadIdx.x == 0) {
            #pragma unroll
            for (int i = 1; i < 4; i++) {
                vmin = fminf(vmin, smin[i]);
                vmax = fmaxf(vmax, smax[i]);
            }
            pmin[blockIdx.x] = vmin;
            pmax[blockIdx.x] = vmax;
        }
    } else {
        int bc = blockIdx.x - 64;              // b*128 + cin (2048)
        const float* src = inp + (size_t)bc * 1024;
        unsigned* dst = xpk + (size_t)bc * 1156;
        #pragma unroll
        for (int i = 0; i < 5; ++i) {
            int idx = threadIdx.x + i * 256;
            if (idx < 1156) {
                int yy = idx / 34, xx = idx - yy * 34;
                float v = 0.0f;
                int ys = yy - 1, xs_ = xx - 1;
                if ((unsigned)ys < 32u && (unsigned)xs_ < 32u) v = src[ys * 32 + xs_];
                unsigned short h = bf16rn(v);
                float hf = __uint_as_float((unsigned)h << 16);
                unsigned short l = bf16rn(v - hf);
                dst[idx] = (unsigned)h | ((unsigned)l << 16);
            }
        }
    }
}

// block-local scale from the 64 partials (identical fp32 op sequence everywhere)
__device__ __forceinline__ float block_scale(const float* pmin, const float* pmax,
                                             float* sca_lds) {
    int t = threadIdx.x;
    if (t < 64) {
        float vmin = pmin[t];
        float vmax = pmax[t];
        #pragma unroll
        for (int off = 32; off > 0; off >>= 1) {
            vmin = fminf(vmin, __shfl_down(vmin, off, 64));
            vmax = fmaxf(vmax, __shfl_down(vmax, off, 64));
        }
        if (t == 0) {
            float tt = __fadd_rn(__fsub_rn(vmax, vmin), 1e-9f);
            *sca_lds = __fdiv_rn(15.0f, tt);
        }
    }
    __syncthreads();
    return *sca_lds;
}

// ---------------- prep: quantize weights into MFMA A-fragment order ----------------
// slot = ((g*18 + r)*8 + mt*2 + khalf)*64 + lane ; 16B per slot (8 bf16, k ascending)
// value(lane, j) = wq[d = 64r + khalf*32 + (lane>>4)*8 + j][m = g*64 + mt*16 + (lane&15)]
__global__ __launch_bounds__(256) void k_quantb(const float* __restrict__ w,
                                                const float* __restrict__ pmin,
                                                const float* __restrict__ pmax,
                                                uv4* __restrict__ wqb) {
    __shared__ float sca;
    float s = block_scale(pmin, pmax, &sca);
    int slot = blockIdx.x * 256 + threadIdx.x;   // 36864 total
    int lane = slot & 63;
    int sub = slot >> 6;
    int khalf = sub & 1;
    int mt = (sub >> 1) & 3;
    int gr = sub >> 3;                 // g*18 + r
    int g = gr / 18, r = gr - g * 18;
    int m = g * 64 + mt * 16 + (lane & 15);
    int dbase = r * 64 + khalf * 32 + (lane >> 4) * 8;
    const float* wp = w + (size_t)m * 1152 + dbase;
    unsigned o[4];
    #pragma unroll
    for (int p = 0; p < 4; ++p) {
        float q0 = rintf(__fmul_rn(wp[2 * p], s));
        float q1 = rintf(__fmul_rn(wp[2 * p + 1], s));
        q0 = fminf(fmaxf(q0, -7.0f), 7.0f);
        q1 = fminf(fmaxf(q1, -7.0f), 7.0f);
        o[p] = (unsigned)bf16rn(q0) | ((unsigned)bf16rn(q1) << 16);
    }
    uv4 v; v.x = o[0]; v.y = o[1]; v.z = o[2]; v.w = o[3];
    wqb[slot] = v;
}

// ---------------- main: barrier-free gather GEMM + prefetch + in-block fix ----------------
__global__ __launch_bounds__(256) void k_main(const unsigned* __restrict__ xpk,
                                              const uv4* __restrict__ wqb,
                                              const float* __restrict__ inp,
                                              const float* __restrict__ weight,
                                              const float* __restrict__ pmin,
                                              const float* __restrict__ pmax,
                                              float* __restrict__ out) {
    __shared__ int ofs_s[1152];        // plane offset for each k: cin*1156+kh*34+kw
    __shared__ unsigned hitbuf[HITCAP];
    __shared__ unsigned hitcnt;
    __shared__ float sca;

    const int t = threadIdx.x;
    if (t == 0) hitcnt = 0u;
    float sc = block_scale(pmin, pmax, &sca);   // also covers the hitcnt init barrier
    for (int k = t; k < 1152; k += 256) {
        int cin = k / 9;
        int rem = k - cin * 9;
        int kh = rem / 3;
        int kw = rem - kh * 3;
        ofs_s[k] = cin * 1156 + kh * 34 + kw;
    }
    __syncthreads();

    const int lane = t & 63;
    const int wv = t >> 6;             // wave id = n-tile
    const int quad = lane >> 4;
    const int nl = lane & 15;
    const int n0 = blockIdx.x * 64;
    const int g = blockIdx.y;
    const int b = n0 >> 10;

    // wave's image-position base (16 consecutive positions within one row)
    const int sy_w = ((n0 & 1023) >> 5) + (wv >> 1);
    const int col0 = (wv & 1) * 16;
    const unsigned* __restrict__ xw =
        xpk + (size_t)b * (128 * 1156) + sy_w * 34 + col0 + nl;
    const uv4* __restrict__ aw = wqb + (size_t)g * (18 * 512) + lane;

    int counts[4][4] = {};

    // ---- prologue: prefetch chunk 0's B-gather u32s into registers ----
    unsigned pb[16];
    #pragma unroll
    for (int q2 = 0; q2 < 16; ++q2) {
        int k = (q2 >> 3) * 32 + quad * 8 + (q2 & 7);
        pb[q2] = xw[ofs_s[k]];
    }

    for (int r = 0; r < 18; ++r) {
        // consume prefetched, issue next chunk's gathers immediately
        unsigned cb[16];
        #pragma unroll
        for (int q2 = 0; q2 < 16; ++q2) cb[q2] = pb[q2];
        if (r < 17) {
            #pragma unroll
            for (int q2 = 0; q2 < 16; ++q2) {
                int k = (r + 1) * 64 + (q2 >> 3) * 32 + quad * 8 + (q2 & 7);
                pb[q2] = xw[ofs_s[k]];
            }
        }

        // ---- repack current B (split packed hi|lo) ----
        short8 bhi[2], blo[2];
        #pragma unroll
        for (int kh2 = 0; kh2 < 2; ++kh2) {
            union { unsigned d[4]; short8 v; } H, L;
            #pragma unroll
            for (int p = 0; p < 4; ++p) {
                unsigned ua = cb[kh2 * 8 + 2 * p], ub = cb[kh2 * 8 + 2 * p + 1];
                H.d[p] = (ua & 0xffffu) | (ub << 16);
                L.d[p] = (ua >> 16) | (ub & 0xffff0000u);
            }
            bhi[kh2] = H.v;
            blo[kh2] = L.v;
        }

        // ---- per m-tile: A frags direct from global (L1-hot), 4 MFMAs, checks ----
        #pragma unroll
        for (int mt = 0; mt < 4; ++mt) {
            short8 af0 = __builtin_bit_cast(short8, aw[r * 512 + (mt * 2 + 0) * 64]);
            short8 af1 = __builtin_bit_cast(short8, aw[r * 512 + (mt * 2 + 1) * 64]);
            f32x4 acc = {0.0f, 0.0f, 0.0f, 0.0f};
            acc = __builtin_amdgcn_mfma_f32_16x16x32_bf16(af0, bhi[0], acc, 0, 0, 0);
            acc = __builtin_amdgcn_mfma_f32_16x16x32_bf16(af1, bhi[1], acc, 0, 0, 0);
            acc = __builtin_amdgcn_mfma_f32_16x16x32_bf16(af0, blo[0], acc, 0, 0, 0);
            acc = __builtin_amdgcn_mfma_f32_16x16x32_bf16(af1, blo[1], acc, 0, 0, 0);
            #pragma unroll
            for (int i = 0; i < 4; ++i) {
                float s = acc[i];
                int ge = (s >= 0.0f) ? 1 : 0;
                counts[mt][i] += ge;
                if (__builtin_fabsf(s) < TAU) {
                    unsigned idx = atomicAdd(&hitcnt, 1u);   // LDS atomic: fast, rare
                    if (idx < (unsigned)HITCAP) {
                        unsigned m = (unsigned)(g * 64 + mt * 16 + quad * 4 + i);
                        unsigned n = (unsigned)(n0 + wv * 16 + nl);
                        hitbuf[idx] = n | ((unsigned)r << 14) | (m << 19) | ((unsigned)ge << 27);
                    }
                }
            }
        }
    }

    // ---- epilogue: C/D layout col=lane&15 (n), row=quad*4+reg (m) ----
    {
        const int n = n0 + wv * 16 + nl;
        const int p = n & 1023;
        #pragma unroll
        for (int mt = 0; mt < 4; ++mt)
            #pragma unroll
            for (int i = 0; i < 4; ++i) {
                int m = g * 64 + mt * 16 + quad * 4 + i;
                out[(((size_t)(b * 256 + m)) << 10) + p] = (float)counts[mt][i];
            }
    }

    // ---- in-block fixup of this block's own hits (R4 k_fix body, verbatim math) ----
    __syncthreads();
    unsigned tot = hitcnt;
    if (tot > (unsigned)HITCAP) tot = (unsigned)HITCAP;
    for (unsigned i = t; i < tot; i += 256) {
        unsigned u = hitbuf[i];
        int n = u & 16383;
        int r = (u >> 14) & 31;
        int m = (u >> 19) & 255;
        int bit = (u >> 27) & 1;
        int bb = n >> 10, p = n & 1023, y = p >> 5, x = p & 31;
        const float* ib = inp + (size_t)bb * (128 * 32 * 32);
        const float* wp = weight + (size_t)m * 1152;
        float s = 0.0f;
        int d = r * 64;
        for (int c = 0; c < 64; ++c, ++d) {
            int ci = d / 9, rem = d - ci * 9;
            int kh = rem / 3, kw = rem - kh * 3;
            int yy = y + kh - 1, xx = x + kw - 1;
            float xv = 0.0f;
            if ((unsigned)yy < 32u && (unsigned)xx < 32u)
                xv = ib[(ci * 32 + yy) * 32 + xx];
            float q = rintf(__fmul_rn(wp[d], sc));
            q = fminf(fmaxf(q, -7.0f), 7.0f);
            s = __fadd_rn(s, __fmul_rn(xv, q));
        }
        int nb = (s >= 0.0f) ? 1 : 0;
        if (nb != bit)
            atomicAdd(&out[(((size_t)(bb * 256 + m)) << 10) + p], nb ? 1.0f : -1.0f);
    }
}

extern "C" void kernel_launch(void* const* d_in, const int* in_sizes, int n_in,
                              void* d_out, int out_size, void* d_ws, size_t ws_size,
                              hipStream_t stream) {
    const float* inp    = (const float*)d_in[0];   // [16,128,32,32]
    const float* weight = (const float*)d_in[1];   // [256,128,3,3]
    float* out = (float*)d_out;                    // [16,256,32,32]

    char* ws = (char*)d_ws;
    float*    pmin  = (float*)(ws + 0);
    float*    pmax  = (float*)(ws + 256);
    uv4*      wqb   = (uv4*)(ws + 1024);          // 589,824 B
    unsigned* xpk   = (unsigned*)(ws + 590848);   // 9,469,952 B

    k_prep<<<2112, 256, 0, stream>>>(weight, inp, pmin, pmax, xpk);
    k_quantb<<<144, 256, 0, stream>>>(weight, pmin, pmax, wqb);

    dim3 grid(256, 4);   // (N/64, M/64)
    k_main<<<grid, 256, 0, stream>>>(xpk, wqb, inp, weight, pmin, pmax, out);
}